// Round 3
// baseline (354.163 us; speedup 1.0000x reference)
//
#include <hip/hip_runtime.h>

typedef __attribute__((ext_vector_type(8))) __bf16 bf16x8;
typedef __attribute__((ext_vector_type(4))) __bf16 bf16x4;
typedef __attribute__((ext_vector_type(4))) float  f32x4;

static constexpr int TSEQ   = 2048;
static constexpr int DMODEL = 1024;
static constexpr int HD     = 64;

// ---------------- convert x (fp32 -> bf16) ----------------
__global__ __launch_bounds__(256) void k_convert_x(const float* __restrict__ x,
                                                   __bf16* __restrict__ xbf) {
  size_t i = ((size_t)blockIdx.x * 256 + threadIdx.x) * 4;
  float4 v = *(const float4*)(x + i);
  bf16x4 o = { (__bf16)v.x, (__bf16)v.y, (__bf16)v.z, (__bf16)v.w };
  *(bf16x4*)(xbf + i) = o;
}

// ---------------- transpose + convert weights (fp32 [K][N] -> bf16 [N][K]) ----------------
__global__ __launch_bounds__(1024) void k_transpose_w(const float* __restrict__ w0,
    const float* __restrict__ w1, const float* __restrict__ w2,
    const float* __restrict__ w3, __bf16* __restrict__ wt_all) {
  __shared__ float tile[32][33];
  const float* w = blockIdx.z == 0 ? w0 : blockIdx.z == 1 ? w1 : blockIdx.z == 2 ? w2 : w3;
  __bf16* out = wt_all + (size_t)blockIdx.z * DMODEL * DMODEL;
  int n0 = blockIdx.x * 32, k0 = blockIdx.y * 32;
  int tx = threadIdx.x, ty = threadIdx.y;
  tile[ty][tx] = w[(size_t)(k0 + ty) * DMODEL + n0 + tx];
  __syncthreads();
  out[(size_t)(n0 + ty) * DMODEL + k0 + tx] = (__bf16)tile[tx][ty];
}

// ---------------- shared GEMM mainloop ----------------
__device__ __forceinline__ void gemm_mainloop(const __bf16* __restrict__ A,
                                              const __bf16* __restrict__ Bt,
                                              int bm, int bn,
                                              __bf16* At, __bf16* Bl,
                                              f32x4 acc[4][4]) {
  const int tid  = threadIdx.x;
  const int lane = tid & 63;
  const int l15  = lane & 15, quad = lane >> 4;
  const int wv   = tid >> 6;
  const int wm   = (wv >> 1) * 64, wn = (wv & 1) * 64;
  for (int k0 = 0; k0 < 1024; k0 += 32) {
    __syncthreads();
    for (int c = tid; c < 512; c += 256) {
      int row = c >> 2, kc = (c & 3) << 3;
      *(bf16x8*)(At + row * 40 + kc) =
          *(const bf16x8*)(A + (size_t)(bm + row) * 1024 + k0 + kc);
      *(bf16x8*)(Bl + row * 40 + kc) =
          *(const bf16x8*)(Bt + (size_t)(bn + row) * 1024 + k0 + kc);
    }
    __syncthreads();
    bf16x8 af[4], bfr[4];
#pragma unroll
    for (int mt = 0; mt < 4; mt++)
      af[mt] = *(const bf16x8*)(At + (wm + mt * 16 + l15) * 40 + quad * 8);
#pragma unroll
    for (int nt = 0; nt < 4; nt++)
      bfr[nt] = *(const bf16x8*)(Bl + (wn + nt * 16 + l15) * 40 + quad * 8);
#pragma unroll
    for (int mt = 0; mt < 4; mt++)
#pragma unroll
      for (int nt = 0; nt < 4; nt++)
        acc[mt][nt] = __builtin_amdgcn_mfma_f32_16x16x32_bf16(
            af[mt], bfr[nt], acc[mt][nt], 0, 0, 0);
  }
}

// ---------------- QKV projection (Q pre-scaled by 1/8) ----------------
__global__ __launch_bounds__(256) void k_gemm_qkv(const __bf16* __restrict__ xbf,
    const __bf16* __restrict__ wt_all, __bf16* __restrict__ qws,
    __bf16* __restrict__ kws, __bf16* __restrict__ vtws) {
  __shared__ __bf16 At[128 * 40];
  __shared__ __bf16 Bl[128 * 40];
  const int which = blockIdx.z;
  const __bf16* wt = wt_all + (size_t)which * DMODEL * DMODEL;
  const int bm = blockIdx.y * 128, bn = blockIdx.x * 128;
  f32x4 acc[4][4];
  const f32x4 z = {0.f, 0.f, 0.f, 0.f};
#pragma unroll
  for (int mt = 0; mt < 4; mt++)
#pragma unroll
    for (int nt = 0; nt < 4; nt++) acc[mt][nt] = z;
  gemm_mainloop(xbf, wt, bm, bn, At, Bl, acc);
  const int lane = threadIdx.x & 63;
  const int l15 = lane & 15, quad = lane >> 4;
  const int wv = threadIdx.x >> 6;
  const int wm = (wv >> 1) * 64, wn = (wv & 1) * 64;
#pragma unroll
  for (int mt = 0; mt < 4; mt++)
#pragma unroll
    for (int nt = 0; nt < 4; nt++)
#pragma unroll
      for (int r = 0; r < 4; r++) {
        int m = bm + wm + mt * 16 + quad * 4 + r;
        int n = bn + wn + nt * 16 + l15;
        int b = m >> 11, t = m & 2047;
        int h = n >> 6,  d = n & 63;
        int bh = b * 16 + h;
        float av = acc[mt][nt][r];
        if (which == 0)      qws[((size_t)bh * TSEQ + t) * HD + d] = (__bf16)(av * 0.125f);
        else if (which == 1) kws[((size_t)bh * TSEQ + t) * HD + d] = (__bf16)av;
        else                 vtws[((size_t)bh * HD + d) * TSEQ + t] = (__bf16)av;
      }
}

// ---------------- flash attention (causal, no-max softmax, split-K, paired qt) ----------------
// Block x handles q-tiles (x, 127-x): total K-tiles ~33 per block -> perfect balance.
// Grid 64x32 = 2048 blocks = 8 blocks/CU exactly. LDS 16.6 KB -> 8 blocks fit.
// Split-K merge via LDS float atomics (ds_add_f32). Only frontier tile is masked.
__global__ __launch_bounds__(256) void k_attn(const __bf16* __restrict__ qws,
    const __bf16* __restrict__ kws, const __bf16* __restrict__ vtws,
    __bf16* __restrict__ ctx) {
  const int bh = blockIdx.y;
  const int tid = threadIdx.x;
  const int lane = tid & 63, wv = tid >> 6;
  const int l15 = lane & 15, quad = lane >> 4;
  const __bf16* qp = qws  + (size_t)bh * TSEQ * HD;
  const __bf16* kp = kws  + (size_t)bh * TSEQ * HD;
  const __bf16* vp = vtws + (size_t)bh * HD * TSEQ;
  const int b = bh >> 4, h = bh & 15;

  __shared__ __bf16 plds[4][16 * 68];   // dword stride 34: writes conflict-free
  __shared__ float  obuf[16][65];
  __shared__ float  lbuf[4][16][16];
  __shared__ float  lrowinv[16];

  const f32x4 z = {0.f, 0.f, 0.f, 0.f};

  for (int half = 0; half < 2; half++) {
    const int qt  = half == 0 ? blockIdx.x : 127 - blockIdx.x;
    const int qr0 = qt * 16;
    const int f   = qt >> 2;              // frontier (masked) K-tile index

    for (int e = tid; e < 16 * 65; e += 256) ((float*)obuf)[e] = 0.f;
    __syncthreads();

    bf16x8 aq[2];
#pragma unroll
    for (int kb = 0; kb < 2; kb++)
      aq[kb] = *(const bf16x8*)(qp + (size_t)(qr0 + l15) * HD + kb * 32 + quad * 8);

    float lpart[4] = {0.f, 0.f, 0.f, 0.f};
    f32x4 acc[4];
#pragma unroll
    for (int dt = 0; dt < 4; dt++) acc[dt] = z;

    // ---- unmasked tiles ----
    for (int it = wv; it < f; it += 4) {
      const int kt0 = it * 64;
      f32x4 s[4];
#pragma unroll
      for (int nt = 0; nt < 4; nt++) s[nt] = z;
#pragma unroll
      for (int nt = 0; nt < 4; nt++)
#pragma unroll
        for (int kb = 0; kb < 2; kb++) {
          bf16x8 bk = *(const bf16x8*)(kp + (size_t)(kt0 + nt * 16 + l15) * HD + kb * 32 + quad * 8);
          s[nt] = __builtin_amdgcn_mfma_f32_16x16x32_bf16(aq[kb], bk, s[nt], 0, 0, 0);
        }
#pragma unroll
      for (int r = 0; r < 4; r++)
#pragma unroll
        for (int nt = 0; nt < 4; nt++) {
          float p = __expf(s[nt][r]);
          lpart[r] += p;
          plds[wv][(quad * 4 + r) * 68 + nt * 16 + l15] = (__bf16)p;
        }
#pragma unroll
      for (int kb = 0; kb < 2; kb++) {
        bf16x8 ap = *(const bf16x8*)(&plds[wv][l15 * 68 + kb * 32 + quad * 8]);
#pragma unroll
        for (int dt = 0; dt < 4; dt++) {
          bf16x8 bvv = *(const bf16x8*)(vp + (size_t)(dt * 16 + l15) * TSEQ + kt0 + kb * 32 + quad * 8);
          acc[dt] = __builtin_amdgcn_mfma_f32_16x16x32_bf16(ap, bvv, acc[dt], 0, 0, 0);
        }
      }
    }

    // ---- frontier (masked) tile, one wave ----
    if ((f & 3) == wv) {
      const int kt0 = f * 64;
      f32x4 s[4];
#pragma unroll
      for (int nt = 0; nt < 4; nt++) s[nt] = z;
#pragma unroll
      for (int nt = 0; nt < 4; nt++)
#pragma unroll
        for (int kb = 0; kb < 2; kb++) {
          bf16x8 bk = *(const bf16x8*)(kp + (size_t)(kt0 + nt * 16 + l15) * HD + kb * 32 + quad * 8);
          s[nt] = __builtin_amdgcn_mfma_f32_16x16x32_bf16(aq[kb], bk, s[nt], 0, 0, 0);
        }
#pragma unroll
      for (int r = 0; r < 4; r++) {
        const int qrow = qr0 + quad * 4 + r;
#pragma unroll
        for (int nt = 0; nt < 4; nt++) {
          int kcol = kt0 + nt * 16 + l15;
          float p = (kcol <= qrow) ? __expf(s[nt][r]) : 0.f;
          lpart[r] += p;
          plds[wv][(quad * 4 + r) * 68 + nt * 16 + l15] = (__bf16)p;
        }
      }
#pragma unroll
      for (int kb = 0; kb < 2; kb++) {
        bf16x8 ap = *(const bf16x8*)(&plds[wv][l15 * 68 + kb * 32 + quad * 8]);
#pragma unroll
        for (int dt = 0; dt < 4; dt++) {
          bf16x8 bvv = *(const bf16x8*)(vp + (size_t)(dt * 16 + l15) * TSEQ + kt0 + kb * 32 + quad * 8);
          acc[dt] = __builtin_amdgcn_mfma_f32_16x16x32_bf16(ap, bvv, acc[dt], 0, 0, 0);
        }
      }
    }

    // ---- split-K merge via LDS atomics ----
#pragma unroll
    for (int dt = 0; dt < 4; dt++)
#pragma unroll
      for (int r = 0; r < 4; r++)
        atomicAdd(&obuf[quad * 4 + r][dt * 16 + l15], acc[dt][r]);
#pragma unroll
    for (int r = 0; r < 4; r++)
      lbuf[wv][quad * 4 + r][l15] = lpart[r];
    __syncthreads();
    if (tid < 16) {
      float lr = 0.f;
#pragma unroll
      for (int w = 0; w < 4; w++)
        for (int j = 0; j < 16; j++) lr += lbuf[w][tid][j];
      lrowinv[tid] = 1.f / lr;
    }
    __syncthreads();
#pragma unroll
    for (int i = 0; i < 4; i++) {
      int e = tid + 256 * i;
      int row = e >> 6, dim = e & 63;
      ctx[((size_t)(b * TSEQ + qr0 + row)) * DMODEL + h * 64 + dim] =
          (__bf16)(obuf[row][dim] * lrowinv[row]);
    }
    __syncthreads();   // protect obuf/plds before next half re-zeroes
  }
}

// ---------------- output projection + bias (fp32 out) ----------------
__global__ __launch_bounds__(256) void k_gemm_out(const __bf16* __restrict__ ctx,
    const __bf16* __restrict__ wot, const float* __restrict__ bo,
    float* __restrict__ out) {
  __shared__ __bf16 At[128 * 40];
  __shared__ __bf16 Bl[128 * 40];
  const int bm = blockIdx.y * 128, bn = blockIdx.x * 128;
  f32x4 acc[4][4];
  const f32x4 z = {0.f, 0.f, 0.f, 0.f};
#pragma unroll
  for (int mt = 0; mt < 4; mt++)
#pragma unroll
    for (int nt = 0; nt < 4; nt++) acc[mt][nt] = z;
  gemm_mainloop(ctx, wot, bm, bn, At, Bl, acc);
  const int lane = threadIdx.x & 63;
  const int l15 = lane & 15, quad = lane >> 4;
  const int wv = threadIdx.x >> 6;
  const int wm = (wv >> 1) * 64, wn = (wv & 1) * 64;
#pragma unroll
  for (int mt = 0; mt < 4; mt++)
#pragma unroll
    for (int nt = 0; nt < 4; nt++)
#pragma unroll
      for (int r = 0; r < 4; r++) {
        int m = bm + wm + mt * 16 + quad * 4 + r;
        int n = bn + wn + nt * 16 + l15;
        out[(size_t)m * DMODEL + n] = acc[mt][nt][r] + bo[n];
      }
}

extern "C" void kernel_launch(void* const* d_in, const int* in_sizes, int n_in,
                              void* d_out, int out_size, void* d_ws, size_t ws_size,
                              hipStream_t stream) {
  const float* x  = (const float*)d_in[0];
  const float* Wq = (const float*)d_in[1];
  const float* Wk = (const float*)d_in[2];
  const float* Wv = (const float*)d_in[3];
  const float* Wo = (const float*)d_in[4];
  const float* bo = (const float*)d_in[5];
  float* out = (float*)d_out;

  __bf16* xbf  = (__bf16*)d_ws;                       // 4096*1024
  __bf16* wt   = xbf  + (size_t)4096 * 1024;          // 4 * 1024*1024
  __bf16* qws  = wt   + (size_t)4 * 1024 * 1024;      // [32][2048][64]
  __bf16* kws  = qws  + (size_t)32 * 2048 * 64;
  __bf16* vtws = kws  + (size_t)32 * 2048 * 64;       // [32][64][2048]
  __bf16* ctx  = xbf;                                 // aliases xbf (dead after QKV)

  k_convert_x<<<4096, 256, 0, stream>>>(x, xbf);
  k_transpose_w<<<dim3(32, 32, 4), dim3(32, 32), 0, stream>>>(Wq, Wk, Wv, Wo, wt);
  k_gemm_qkv<<<dim3(8, 32, 3), 256, 0, stream>>>(xbf, wt, qws, kws, vtws);
  k_attn<<<dim3(64, 32), 256, 0, stream>>>(qws, kws, vtws, ctx);
  k_gemm_out<<<dim3(8, 32), 256, 0, stream>>>(ctx, wt + (size_t)3 * 1024 * 1024, bo, out);
}

// Round 4
// 335.902 us; speedup vs baseline: 1.0544x; 1.0544x over previous
//
#include <hip/hip_runtime.h>

typedef __attribute__((ext_vector_type(8))) __bf16 bf16x8;
typedef __attribute__((ext_vector_type(4))) __bf16 bf16x4;
typedef __attribute__((ext_vector_type(4))) float  f32x4;

static constexpr int TSEQ    = 2048;
static constexpr int DMODEL  = 1024;
static constexpr int HD      = 64;
static constexpr int VSTRIDE = 2080;   // 2048+32: 4160B row stride breaks 4KB L2-channel aliasing

// ---------------- convert x (fp32 -> bf16) ----------------
__global__ __launch_bounds__(256) void k_convert_x(const float* __restrict__ x,
                                                   __bf16* __restrict__ xbf) {
  size_t i = ((size_t)blockIdx.x * 256 + threadIdx.x) * 4;
  float4 v = *(const float4*)(x + i);
  bf16x4 o = { (__bf16)v.x, (__bf16)v.y, (__bf16)v.z, (__bf16)v.w };
  *(bf16x4*)(xbf + i) = o;
}

// ---------------- transpose + convert weights (fp32 [K][N] -> bf16 [N][K]) ----------------
__global__ __launch_bounds__(1024) void k_transpose_w(const float* __restrict__ w0,
    const float* __restrict__ w1, const float* __restrict__ w2,
    const float* __restrict__ w3, __bf16* __restrict__ wt_all) {
  __shared__ float tile[32][33];
  const float* w = blockIdx.z == 0 ? w0 : blockIdx.z == 1 ? w1 : blockIdx.z == 2 ? w2 : w3;
  __bf16* out = wt_all + (size_t)blockIdx.z * DMODEL * DMODEL;
  int n0 = blockIdx.x * 32, k0 = blockIdx.y * 32;
  int tx = threadIdx.x, ty = threadIdx.y;
  tile[ty][tx] = w[(size_t)(k0 + ty) * DMODEL + n0 + tx];
  __syncthreads();
  out[(size_t)(n0 + ty) * DMODEL + k0 + tx] = (__bf16)tile[tx][ty];
}

// ---------------- shared GEMM mainloop ----------------
__device__ __forceinline__ void gemm_mainloop(const __bf16* __restrict__ A,
                                              const __bf16* __restrict__ Bt,
                                              int bm, int bn,
                                              __bf16* At, __bf16* Bl,
                                              f32x4 acc[4][4]) {
  const int tid  = threadIdx.x;
  const int lane = tid & 63;
  const int l15  = lane & 15, quad = lane >> 4;
  const int wv   = tid >> 6;
  const int wm   = (wv >> 1) * 64, wn = (wv & 1) * 64;
  for (int k0 = 0; k0 < 1024; k0 += 32) {
    __syncthreads();
    for (int c = tid; c < 512; c += 256) {
      int row = c >> 2, kc = (c & 3) << 3;
      *(bf16x8*)(At + row * 40 + kc) =
          *(const bf16x8*)(A + (size_t)(bm + row) * 1024 + k0 + kc);
      *(bf16x8*)(Bl + row * 40 + kc) =
          *(const bf16x8*)(Bt + (size_t)(bn + row) * 1024 + k0 + kc);
    }
    __syncthreads();
    bf16x8 af[4], bfr[4];
#pragma unroll
    for (int mt = 0; mt < 4; mt++)
      af[mt] = *(const bf16x8*)(At + (wm + mt * 16 + l15) * 40 + quad * 8);
#pragma unroll
    for (int nt = 0; nt < 4; nt++)
      bfr[nt] = *(const bf16x8*)(Bl + (wn + nt * 16 + l15) * 40 + quad * 8);
#pragma unroll
    for (int mt = 0; mt < 4; mt++)
#pragma unroll
      for (int nt = 0; nt < 4; nt++)
        acc[mt][nt] = __builtin_amdgcn_mfma_f32_16x16x32_bf16(
            af[mt], bfr[nt], acc[mt][nt], 0, 0, 0);
  }
}

// ---------------- QKV projection (Q pre-scaled by 1/8) ----------------
__global__ __launch_bounds__(256) void k_gemm_qkv(const __bf16* __restrict__ xbf,
    const __bf16* __restrict__ wt_all, __bf16* __restrict__ qws,
    __bf16* __restrict__ kws, __bf16* __restrict__ vtws) {
  __shared__ __bf16 At[128 * 40];
  __shared__ __bf16 Bl[128 * 40];
  const int which = blockIdx.z;
  const __bf16* wt = wt_all + (size_t)which * DMODEL * DMODEL;
  const int bm = blockIdx.y * 128, bn = blockIdx.x * 128;
  f32x4 acc[4][4];
  const f32x4 z = {0.f, 0.f, 0.f, 0.f};
#pragma unroll
  for (int mt = 0; mt < 4; mt++)
#pragma unroll
    for (int nt = 0; nt < 4; nt++) acc[mt][nt] = z;
  gemm_mainloop(xbf, wt, bm, bn, At, Bl, acc);
  const int lane = threadIdx.x & 63;
  const int l15 = lane & 15, quad = lane >> 4;
  const int wv = threadIdx.x >> 6;
  const int wm = (wv >> 1) * 64, wn = (wv & 1) * 64;
#pragma unroll
  for (int mt = 0; mt < 4; mt++)
#pragma unroll
    for (int nt = 0; nt < 4; nt++)
#pragma unroll
      for (int r = 0; r < 4; r++) {
        int m = bm + wm + mt * 16 + quad * 4 + r;
        int n = bn + wn + nt * 16 + l15;
        int b = m >> 11, t = m & 2047;
        int h = n >> 6,  d = n & 63;
        int bh = b * 16 + h;
        float av = acc[mt][nt][r];
        if (which == 0)      qws[((size_t)bh * TSEQ + t) * HD + d] = (__bf16)(av * 0.125f);
        else if (which == 1) kws[((size_t)bh * TSEQ + t) * HD + d] = (__bf16)av;
        else                 vtws[((size_t)bh * HD + d) * VSTRIDE + t] = (__bf16)av;
      }
}

// ---------------- flash attention (causal, no-max softmax, split-K, paired qt) ----------------
__global__ __launch_bounds__(256) void k_attn(const __bf16* __restrict__ qws,
    const __bf16* __restrict__ kws, const __bf16* __restrict__ vtws,
    __bf16* __restrict__ ctx) {
  const int bh = blockIdx.y;
  const int tid = threadIdx.x;
  const int lane = tid & 63, wv = tid >> 6;
  const int l15 = lane & 15, quad = lane >> 4;
  const __bf16* qp = qws  + (size_t)bh * TSEQ * HD;
  const __bf16* kp = kws  + (size_t)bh * TSEQ * HD;
  const __bf16* vp = vtws + (size_t)bh * HD * VSTRIDE;
  const int b = bh >> 4, h = bh & 15;

  __shared__ __bf16 plds[4][16 * 68];   // dword stride 34: writes conflict-free
  __shared__ float  obuf[16][65];
  __shared__ float  lbuf[4][16][16];
  __shared__ float  lrowinv[16];

  const f32x4 z = {0.f, 0.f, 0.f, 0.f};

  for (int half = 0; half < 2; half++) {
    const int qt  = half == 0 ? blockIdx.x : 127 - blockIdx.x;
    const int qr0 = qt * 16;
    const int f   = qt >> 2;              // frontier (masked) K-tile index

    for (int e = tid; e < 16 * 65; e += 256) ((float*)obuf)[e] = 0.f;
    __syncthreads();

    bf16x8 aq[2];
#pragma unroll
    for (int kb = 0; kb < 2; kb++)
      aq[kb] = *(const bf16x8*)(qp + (size_t)(qr0 + l15) * HD + kb * 32 + quad * 8);

    float lpart[4] = {0.f, 0.f, 0.f, 0.f};
    f32x4 acc[4];
#pragma unroll
    for (int dt = 0; dt < 4; dt++) acc[dt] = z;

    // ---- unmasked tiles ----
    for (int it = wv; it < f; it += 4) {
      const int kt0 = it * 64;
      f32x4 s[4];
#pragma unroll
      for (int nt = 0; nt < 4; nt++) s[nt] = z;
#pragma unroll
      for (int nt = 0; nt < 4; nt++)
#pragma unroll
        for (int kb = 0; kb < 2; kb++) {
          bf16x8 bk = *(const bf16x8*)(kp + (size_t)(kt0 + nt * 16 + l15) * HD + kb * 32 + quad * 8);
          s[nt] = __builtin_amdgcn_mfma_f32_16x16x32_bf16(aq[kb], bk, s[nt], 0, 0, 0);
        }
#pragma unroll
      for (int r = 0; r < 4; r++)
#pragma unroll
        for (int nt = 0; nt < 4; nt++) {
          float p = __expf(s[nt][r]);
          lpart[r] += p;
          plds[wv][(quad * 4 + r) * 68 + nt * 16 + l15] = (__bf16)p;
        }
#pragma unroll
      for (int kb = 0; kb < 2; kb++) {
        bf16x8 ap = *(const bf16x8*)(&plds[wv][l15 * 68 + kb * 32 + quad * 8]);
#pragma unroll
        for (int dt = 0; dt < 4; dt++) {
          bf16x8 bvv = *(const bf16x8*)(vp + (size_t)(dt * 16 + l15) * VSTRIDE + kt0 + kb * 32 + quad * 8);
          acc[dt] = __builtin_amdgcn_mfma_f32_16x16x32_bf16(ap, bvv, acc[dt], 0, 0, 0);
        }
      }
    }

    // ---- frontier (masked) tile, one wave ----
    if ((f & 3) == wv) {
      const int kt0 = f * 64;
      f32x4 s[4];
#pragma unroll
      for (int nt = 0; nt < 4; nt++) s[nt] = z;
#pragma unroll
      for (int nt = 0; nt < 4; nt++)
#pragma unroll
        for (int kb = 0; kb < 2; kb++) {
          bf16x8 bk = *(const bf16x8*)(kp + (size_t)(kt0 + nt * 16 + l15) * HD + kb * 32 + quad * 8);
          s[nt] = __builtin_amdgcn_mfma_f32_16x16x32_bf16(aq[kb], bk, s[nt], 0, 0, 0);
        }
#pragma unroll
      for (int r = 0; r < 4; r++) {
        const int qrow = qr0 + quad * 4 + r;
#pragma unroll
        for (int nt = 0; nt < 4; nt++) {
          int kcol = kt0 + nt * 16 + l15;
          float p = (kcol <= qrow) ? __expf(s[nt][r]) : 0.f;
          lpart[r] += p;
          plds[wv][(quad * 4 + r) * 68 + nt * 16 + l15] = (__bf16)p;
        }
      }
#pragma unroll
      for (int kb = 0; kb < 2; kb++) {
        bf16x8 ap = *(const bf16x8*)(&plds[wv][l15 * 68 + kb * 32 + quad * 8]);
#pragma unroll
        for (int dt = 0; dt < 4; dt++) {
          bf16x8 bvv = *(const bf16x8*)(vp + (size_t)(dt * 16 + l15) * VSTRIDE + kt0 + kb * 32 + quad * 8);
          acc[dt] = __builtin_amdgcn_mfma_f32_16x16x32_bf16(ap, bvv, acc[dt], 0, 0, 0);
        }
      }
    }

    // ---- split-K merge via LDS atomics ----
#pragma unroll
    for (int dt = 0; dt < 4; dt++)
#pragma unroll
      for (int r = 0; r < 4; r++)
        atomicAdd(&obuf[quad * 4 + r][dt * 16 + l15], acc[dt][r]);
#pragma unroll
    for (int r = 0; r < 4; r++)
      lbuf[wv][quad * 4 + r][l15] = lpart[r];
    __syncthreads();
    if (tid < 16) {
      float lr = 0.f;
#pragma unroll
      for (int w = 0; w < 4; w++)
        for (int j = 0; j < 16; j++) lr += lbuf[w][tid][j];
      lrowinv[tid] = 1.f / lr;
    }
    __syncthreads();
#pragma unroll
    for (int i = 0; i < 4; i++) {
      int e = tid + 256 * i;
      int row = e >> 6, dim = e & 63;
      ctx[((size_t)(b * TSEQ + qr0 + row)) * DMODEL + h * 64 + dim] =
          (__bf16)(obuf[row][dim] * lrowinv[row]);
    }
    __syncthreads();   // protect obuf/plds before next half re-zeroes
  }
}

// ---------------- output projection + bias (fp32 out) ----------------
__global__ __launch_bounds__(256) void k_gemm_out(const __bf16* __restrict__ ctx,
    const __bf16* __restrict__ wot, const float* __restrict__ bo,
    float* __restrict__ out) {
  __shared__ __bf16 At[128 * 40];
  __shared__ __bf16 Bl[128 * 40];
  const int bm = blockIdx.y * 128, bn = blockIdx.x * 128;
  f32x4 acc[4][4];
  const f32x4 z = {0.f, 0.f, 0.f, 0.f};
#pragma unroll
  for (int mt = 0; mt < 4; mt++)
#pragma unroll
    for (int nt = 0; nt < 4; nt++) acc[mt][nt] = z;
  gemm_mainloop(ctx, wot, bm, bn, At, Bl, acc);
  const int lane = threadIdx.x & 63;
  const int l15 = lane & 15, quad = lane >> 4;
  const int wv = threadIdx.x >> 6;
  const int wm = (wv >> 1) * 64, wn = (wv & 1) * 64;
#pragma unroll
  for (int mt = 0; mt < 4; mt++)
#pragma unroll
    for (int nt = 0; nt < 4; nt++)
#pragma unroll
      for (int r = 0; r < 4; r++) {
        int m = bm + wm + mt * 16 + quad * 4 + r;
        int n = bn + wn + nt * 16 + l15;
        out[(size_t)m * DMODEL + n] = acc[mt][nt][r] + bo[n];
      }
}

extern "C" void kernel_launch(void* const* d_in, const int* in_sizes, int n_in,
                              void* d_out, int out_size, void* d_ws, size_t ws_size,
                              hipStream_t stream) {
  const float* x  = (const float*)d_in[0];
  const float* Wq = (const float*)d_in[1];
  const float* Wk = (const float*)d_in[2];
  const float* Wv = (const float*)d_in[3];
  const float* Wo = (const float*)d_in[4];
  const float* bo = (const float*)d_in[5];
  float* out = (float*)d_out;

  __bf16* xbf  = (__bf16*)d_ws;                       // 4096*1024
  __bf16* wt   = xbf  + (size_t)4096 * 1024;          // 4 * 1024*1024
  __bf16* qws  = wt   + (size_t)4 * 1024 * 1024;      // [32][2048][64]
  __bf16* kws  = qws  + (size_t)32 * 2048 * 64;
  __bf16* vtws = kws  + (size_t)32 * 2048 * 64;       // [32][64][VSTRIDE]
  __bf16* ctx  = xbf;                                 // aliases xbf (dead after QKV)

  k_convert_x<<<4096, 256, 0, stream>>>(x, xbf);
  k_transpose_w<<<dim3(32, 32, 4), dim3(32, 32), 0, stream>>>(Wq, Wk, Wv, Wo, wt);
  k_gemm_qkv<<<dim3(8, 32, 3), 256, 0, stream>>>(xbf, wt, qws, kws, vtws);
  k_attn<<<dim3(64, 32), 256, 0, stream>>>(qws, kws, vtws, ctx);
  k_gemm_out<<<dim3(8, 32), 256, 0, stream>>>(ctx, wt + (size_t)3 * 1024 * 1024, bo, out);
}

// Round 5
// 217.713 us; speedup vs baseline: 1.6267x; 1.5429x over previous
//
#include <hip/hip_runtime.h>

typedef __attribute__((ext_vector_type(8))) __bf16 bf16x8;
typedef __attribute__((ext_vector_type(4))) __bf16 bf16x4;
typedef __attribute__((ext_vector_type(4))) float  f32x4;

static constexpr int TSEQ    = 2048;
static constexpr int DMODEL  = 1024;
static constexpr int HD      = 64;
static constexpr int VSTRIDE = 2080;   // V^T row stride (breaks 4KB L2-channel aliasing)
static constexpr int LSTR    = 72;     // LDS tile row stride (36 dwords: optimal b128 spread)

// ---------------- convert x (fp32 -> bf16) ----------------
__global__ __launch_bounds__(256) void k_convert_x(const float* __restrict__ x,
                                                   __bf16* __restrict__ xbf) {
  size_t i = ((size_t)blockIdx.x * 256 + threadIdx.x) * 4;
  float4 v = *(const float4*)(x + i);
  bf16x4 o = { (__bf16)v.x, (__bf16)v.y, (__bf16)v.z, (__bf16)v.w };
  *(bf16x4*)(xbf + i) = o;
}

// ---------------- transpose + convert weights (fp32 [K][N] -> bf16 [N][K]) ----------------
__global__ __launch_bounds__(1024) void k_transpose_w(const float* __restrict__ w0,
    const float* __restrict__ w1, const float* __restrict__ w2,
    const float* __restrict__ w3, __bf16* __restrict__ wt_all) {
  __shared__ float tile[32][33];
  const float* w = blockIdx.z == 0 ? w0 : blockIdx.z == 1 ? w1 : blockIdx.z == 2 ? w2 : w3;
  __bf16* out = wt_all + (size_t)blockIdx.z * DMODEL * DMODEL;
  int n0 = blockIdx.x * 32, k0 = blockIdx.y * 32;
  int tx = threadIdx.x, ty = threadIdx.y;
  tile[ty][tx] = w[(size_t)(k0 + ty) * DMODEL + n0 + tx];
  __syncthreads();
  out[(size_t)(n0 + ty) * DMODEL + k0 + tx] = (__bf16)tile[tx][ty];
}

// ---------------- shared GEMM mainloop ----------------
__device__ __forceinline__ void gemm_mainloop(const __bf16* __restrict__ A,
                                              const __bf16* __restrict__ Bt,
                                              int bm, int bn,
                                              __bf16* At, __bf16* Bl,
                                              f32x4 acc[4][4]) {
  const int tid  = threadIdx.x;
  const int lane = tid & 63;
  const int l15  = lane & 15, quad = lane >> 4;
  const int wv   = tid >> 6;
  const int wm   = (wv >> 1) * 64, wn = (wv & 1) * 64;
  for (int k0 = 0; k0 < 1024; k0 += 32) {
    __syncthreads();
    for (int c = tid; c < 512; c += 256) {
      int row = c >> 2, kc = (c & 3) << 3;
      *(bf16x8*)(At + row * 40 + kc) =
          *(const bf16x8*)(A + (size_t)(bm + row) * 1024 + k0 + kc);
      *(bf16x8*)(Bl + row * 40 + kc) =
          *(const bf16x8*)(Bt + (size_t)(bn + row) * 1024 + k0 + kc);
    }
    __syncthreads();
    bf16x8 af[4], bfr[4];
#pragma unroll
    for (int mt = 0; mt < 4; mt++)
      af[mt] = *(const bf16x8*)(At + (wm + mt * 16 + l15) * 40 + quad * 8);
#pragma unroll
    for (int nt = 0; nt < 4; nt++)
      bfr[nt] = *(const bf16x8*)(Bl + (wn + nt * 16 + l15) * 40 + quad * 8);
#pragma unroll
    for (int mt = 0; mt < 4; mt++)
#pragma unroll
      for (int nt = 0; nt < 4; nt++)
        acc[mt][nt] = __builtin_amdgcn_mfma_f32_16x16x32_bf16(
            af[mt], bfr[nt], acc[mt][nt], 0, 0, 0);
  }
}

// ---------------- QKV projection (Q pre-scaled by 1/8) ----------------
__global__ __launch_bounds__(256) void k_gemm_qkv(const __bf16* __restrict__ xbf,
    const __bf16* __restrict__ wt_all, __bf16* __restrict__ qws,
    __bf16* __restrict__ kws, __bf16* __restrict__ vtws) {
  __shared__ __bf16 At[128 * 40];
  __shared__ __bf16 Bl[128 * 40];
  const int which = blockIdx.z;
  const __bf16* wt = wt_all + (size_t)which * DMODEL * DMODEL;
  const int bm = blockIdx.y * 128, bn = blockIdx.x * 128;
  f32x4 acc[4][4];
  const f32x4 z = {0.f, 0.f, 0.f, 0.f};
#pragma unroll
  for (int mt = 0; mt < 4; mt++)
#pragma unroll
    for (int nt = 0; nt < 4; nt++) acc[mt][nt] = z;
  gemm_mainloop(xbf, wt, bm, bn, At, Bl, acc);
  const int lane = threadIdx.x & 63;
  const int l15 = lane & 15, quad = lane >> 4;
  const int wv = threadIdx.x >> 6;
  const int wm = (wv >> 1) * 64, wn = (wv & 1) * 64;
#pragma unroll
  for (int mt = 0; mt < 4; mt++)
#pragma unroll
    for (int nt = 0; nt < 4; nt++)
#pragma unroll
      for (int r = 0; r < 4; r++) {
        int m = bm + wm + mt * 16 + quad * 4 + r;
        int n = bn + wn + nt * 16 + l15;
        int b = m >> 11, t = m & 2047;
        int h = n >> 6,  d = n & 63;
        int bh = b * 16 + h;
        float av = acc[mt][nt][r];
        if (which == 0)      qws[((size_t)bh * TSEQ + t) * HD + d] = (__bf16)(av * 0.125f);
        else if (which == 1) kws[((size_t)bh * TSEQ + t) * HD + d] = (__bf16)av;
        else                 vtws[((size_t)bh * HD + d) * VSTRIDE + t] = (__bf16)av;
      }
}

// ---------------- flash attention: LDS-staged K/V shared by 4 waves ----------------
// Block = 64 q-rows (4 waves x 16). Block x does q-block pair (x, 31-x): 33 tiles each.
// Grid 16x32 = 512 blocks = 2/CU. K/V tiles double-buffered in LDS with one-iteration
// register prefetch: ONE vmcnt wait per tile (vs 16 serialized in R4), 4x less L2 traffic.
__global__ __launch_bounds__(256) void k_attn(const __bf16* __restrict__ qws,
    const __bf16* __restrict__ kws, const __bf16* __restrict__ vtws,
    __bf16* __restrict__ ctx) {
  const int qb0 = blockIdx.x, qb1 = 31 - qb0;
  const int bh  = blockIdx.y;
  const int tid = threadIdx.x;
  const int lane = tid & 63, wv = tid >> 6;
  const int l15 = lane & 15, quad = lane >> 4;
  const __bf16* qp = qws  + (size_t)bh * TSEQ * HD;
  const __bf16* kp = kws  + (size_t)bh * TSEQ * HD;
  const __bf16* vp = vtws + (size_t)bh * HD * VSTRIDE;
  const int b = bh >> 4, h = bh & 15;

  __shared__ __bf16 kbuf[2][64 * LSTR];
  __shared__ __bf16 vbuf[2][64 * LSTR];
  __shared__ __bf16 plds[4][16 * 68];

  const f32x4 z = {0.f, 0.f, 0.f, 0.f};
  const int sr = tid >> 3, sc = (tid & 7) * 8;   // staging row / col-offset (elements)

  // Q fragments for both halves
  const int qr0a = qb0 * 64 + wv * 16;
  const int qr0b = qb1 * 64 + wv * 16;
  bf16x8 aq0[2], aq1[2];
#pragma unroll
  for (int kb = 0; kb < 2; kb++) {
    aq0[kb] = *(const bf16x8*)(qp + (size_t)(qr0a + l15) * HD + kb * 32 + quad * 8);
    aq1[kb] = *(const bf16x8*)(qp + (size_t)(qr0b + l15) * HD + kb * 32 + quad * 8);
  }

  bf16x8 kreg[2], vreg[2];
  // prologue: stage tile s=0 (kt0 = 0)
  kreg[0] = *(const bf16x8*)(kp + (size_t)sr * HD + sc);
  kreg[1] = *(const bf16x8*)(kp + (size_t)(sr + 32) * HD + sc);
  vreg[0] = *(const bf16x8*)(vp + (size_t)sr * VSTRIDE + sc);
  vreg[1] = *(const bf16x8*)(vp + (size_t)(sr + 32) * VSTRIDE + sc);
  *(bf16x8*)(kbuf[0] + sr * LSTR + sc)        = kreg[0];
  *(bf16x8*)(kbuf[0] + (sr + 32) * LSTR + sc) = kreg[1];
  *(bf16x8*)(vbuf[0] + sr * LSTR + sc)        = vreg[0];
  *(bf16x8*)(vbuf[0] + (sr + 32) * LSTR + sc) = vreg[1];
  __syncthreads();

  float lpart[4] = {0.f, 0.f, 0.f, 0.f};
  f32x4 acc[4];
#pragma unroll
  for (int dt = 0; dt < 4; dt++) acc[dt] = z;

  for (int s = 0; s < 33; s++) {
    const int cur = s & 1;
    const bool h0 = (s <= qb0);
    const bool masked = (s == qb0) || (s == 32);

    // prefetch tile s+1 into regs (global, async)
    if (s + 1 < 33) {
      const int ktn = (s + 1 <= qb0) ? (s + 1) * 64 : (s - qb0) * 64;
      kreg[0] = *(const bf16x8*)(kp + (size_t)(ktn + sr) * HD + sc);
      kreg[1] = *(const bf16x8*)(kp + (size_t)(ktn + sr + 32) * HD + sc);
      vreg[0] = *(const bf16x8*)(vp + (size_t)sr * VSTRIDE + ktn + sc);
      vreg[1] = *(const bf16x8*)(vp + (size_t)(sr + 32) * VSTRIDE + ktn + sc);
    }

    // ---- compute tile s from LDS ----
    const __bf16* kb_ = kbuf[cur];
    const __bf16* vb_ = vbuf[cur];
    f32x4 sarr[4];
#pragma unroll
    for (int nt = 0; nt < 4; nt++) sarr[nt] = z;
#pragma unroll
    for (int nt = 0; nt < 4; nt++)
#pragma unroll
      for (int kb = 0; kb < 2; kb++) {
        bf16x8 bk = *(const bf16x8*)(kb_ + (nt * 16 + l15) * LSTR + kb * 32 + quad * 8);
        bf16x8 a  = h0 ? aq0[kb] : aq1[kb];
        sarr[nt] = __builtin_amdgcn_mfma_f32_16x16x32_bf16(a, bk, sarr[nt], 0, 0, 0);
      }
    if (masked) {
#pragma unroll
      for (int r = 0; r < 4; r++) {
        const int qloc = wv * 16 + quad * 4 + r;   // local row within 64
#pragma unroll
        for (int nt = 0; nt < 4; nt++) {
          int kloc = nt * 16 + l15;
          float p = (kloc <= qloc) ? __expf(sarr[nt][r]) : 0.f;
          lpart[r] += p;
          plds[wv][(quad * 4 + r) * 68 + nt * 16 + l15] = (__bf16)p;
        }
      }
    } else {
#pragma unroll
      for (int r = 0; r < 4; r++)
#pragma unroll
        for (int nt = 0; nt < 4; nt++) {
          float p = __expf(sarr[nt][r]);
          lpart[r] += p;
          plds[wv][(quad * 4 + r) * 68 + nt * 16 + l15] = (__bf16)p;
        }
    }
#pragma unroll
    for (int kb = 0; kb < 2; kb++) {
      bf16x8 ap = *(const bf16x8*)(&plds[wv][l15 * 68 + kb * 32 + quad * 8]);
#pragma unroll
      for (int dt = 0; dt < 4; dt++) {
        bf16x8 bvv = *(const bf16x8*)(vb_ + (dt * 16 + l15) * LSTR + kb * 32 + quad * 8);
        acc[dt] = __builtin_amdgcn_mfma_f32_16x16x32_bf16(ap, bvv, acc[dt], 0, 0, 0);
      }
    }

    // ---- store prefetched tile into the other buffer ----
    if (s + 1 < 33) {
      const int nxt = cur ^ 1;
      *(bf16x8*)(kbuf[nxt] + sr * LSTR + sc)        = kreg[0];
      *(bf16x8*)(kbuf[nxt] + (sr + 32) * LSTR + sc) = kreg[1];
      *(bf16x8*)(vbuf[nxt] + sr * LSTR + sc)        = vreg[0];
      *(bf16x8*)(vbuf[nxt] + (sr + 32) * LSTR + sc) = vreg[1];
    }
    __syncthreads();

    // ---- end of a half: finalize and reset ----
    if (masked) {
      const int qr0 = h0 ? qr0a : qr0b;
#pragma unroll
      for (int r = 0; r < 4; r++) {
        float l = lpart[r];
        l += __shfl_xor(l, 1, 64);
        l += __shfl_xor(l, 2, 64);
        l += __shfl_xor(l, 4, 64);
        l += __shfl_xor(l, 8, 64);
        float linv = 1.f / l;
        const int qrow = qr0 + quad * 4 + r;
#pragma unroll
        for (int dt = 0; dt < 4; dt++)
          ctx[((size_t)(b * TSEQ + qrow)) * DMODEL + h * 64 + dt * 16 + l15] =
              (__bf16)(acc[dt][r] * linv);
        lpart[r] = 0.f;
      }
#pragma unroll
      for (int dt = 0; dt < 4; dt++) acc[dt] = z;
    }
  }
}

// ---------------- output projection + bias (fp32 out) ----------------
__global__ __launch_bounds__(256) void k_gemm_out(const __bf16* __restrict__ ctx,
    const __bf16* __restrict__ wot, const float* __restrict__ bo,
    float* __restrict__ out) {
  __shared__ __bf16 At[128 * 40];
  __shared__ __bf16 Bl[128 * 40];
  const int bm = blockIdx.y * 128, bn = blockIdx.x * 128;
  f32x4 acc[4][4];
  const f32x4 z = {0.f, 0.f, 0.f, 0.f};
#pragma unroll
  for (int mt = 0; mt < 4; mt++)
#pragma unroll
    for (int nt = 0; nt < 4; nt++) acc[mt][nt] = z;
  gemm_mainloop(ctx, wot, bm, bn, At, Bl, acc);
  const int lane = threadIdx.x & 63;
  const int l15 = lane & 15, quad = lane >> 4;
  const int wv = threadIdx.x >> 6;
  const int wm = (wv >> 1) * 64, wn = (wv & 1) * 64;
#pragma unroll
  for (int mt = 0; mt < 4; mt++)
#pragma unroll
    for (int nt = 0; nt < 4; nt++)
#pragma unroll
      for (int r = 0; r < 4; r++) {
        int m = bm + wm + mt * 16 + quad * 4 + r;
        int n = bn + wn + nt * 16 + l15;
        out[(size_t)m * DMODEL + n] = acc[mt][nt][r] + bo[n];
      }
}

extern "C" void kernel_launch(void* const* d_in, const int* in_sizes, int n_in,
                              void* d_out, int out_size, void* d_ws, size_t ws_size,
                              hipStream_t stream) {
  const float* x  = (const float*)d_in[0];
  const float* Wq = (const float*)d_in[1];
  const float* Wk = (const float*)d_in[2];
  const float* Wv = (const float*)d_in[3];
  const float* Wo = (const float*)d_in[4];
  const float* bo = (const float*)d_in[5];
  float* out = (float*)d_out;

  __bf16* xbf  = (__bf16*)d_ws;                       // 4096*1024
  __bf16* wt   = xbf  + (size_t)4096 * 1024;          // 4 * 1024*1024
  __bf16* qws  = wt   + (size_t)4 * 1024 * 1024;      // [32][2048][64]
  __bf16* kws  = qws  + (size_t)32 * 2048 * 64;
  __bf16* vtws = kws  + (size_t)32 * 2048 * 64;       // [32][64][VSTRIDE]
  __bf16* ctx  = xbf;                                 // aliases xbf (dead after QKV)

  k_convert_x<<<4096, 256, 0, stream>>>(x, xbf);
  k_transpose_w<<<dim3(32, 32, 4), dim3(32, 32), 0, stream>>>(Wq, Wk, Wv, Wo, wt);
  k_gemm_qkv<<<dim3(8, 32, 3), 256, 0, stream>>>(xbf, wt, qws, kws, vtws);
  k_attn<<<dim3(16, 32), 256, 0, stream>>>(qws, kws, vtws, ctx);
  k_gemm_out<<<dim3(8, 32), 256, 0, stream>>>(ctx, wt + (size_t)3 * 1024 * 1024, bo, out);
}

// Round 6
// 199.605 us; speedup vs baseline: 1.7743x; 1.0907x over previous
//
#include <hip/hip_runtime.h>

typedef __attribute__((ext_vector_type(8))) __bf16 bf16x8;
typedef __attribute__((ext_vector_type(4))) __bf16 bf16x4;
typedef __attribute__((ext_vector_type(4))) float  f32x4;

static constexpr int TSEQ    = 2048;
static constexpr int DMODEL  = 1024;
static constexpr int HD      = 64;
static constexpr int VSTRIDE = 2080;   // V^T row stride (breaks 4KB L2-channel aliasing)
static constexpr int LSTR    = 72;     // attn LDS tile row stride

// ---------------- convert x (fp32 -> bf16) ----------------
__global__ __launch_bounds__(256) void k_convert_x(const float* __restrict__ x,
                                                   __bf16* __restrict__ xbf) {
  size_t i = ((size_t)blockIdx.x * 256 + threadIdx.x) * 4;
  float4 v = *(const float4*)(x + i);
  bf16x4 o = { (__bf16)v.x, (__bf16)v.y, (__bf16)v.z, (__bf16)v.w };
  *(bf16x4*)(xbf + i) = o;
}

// ---------------- transpose + convert weights (fp32 [K][N] -> bf16 [N][K]) ----------------
__global__ __launch_bounds__(1024) void k_transpose_w(const float* __restrict__ w0,
    const float* __restrict__ w1, const float* __restrict__ w2,
    const float* __restrict__ w3, __bf16* __restrict__ wt_all) {
  __shared__ float tile[32][33];
  const float* w = blockIdx.z == 0 ? w0 : blockIdx.z == 1 ? w1 : blockIdx.z == 2 ? w2 : w3;
  __bf16* out = wt_all + (size_t)blockIdx.z * DMODEL * DMODEL;
  int n0 = blockIdx.x * 32, k0 = blockIdx.y * 32;
  int tx = threadIdx.x, ty = threadIdx.y;
  tile[ty][tx] = w[(size_t)(k0 + ty) * DMODEL + n0 + tx];
  __syncthreads();
  out[(size_t)(n0 + ty) * DMODEL + k0 + tx] = (__bf16)tile[tx][ty];
}

// ---------------- m97-style GEMM mainloop: global_load_lds width-16 staging ----------------
// A: MxK row-major bf16; Bt: NxK row-major bf16. 128x128 block tile, BK=32.
// LDS tiles UNPADDED 128x32 (async-LDS lane-order constraint; also optimal 8-phase
// b128 frag reads: 8 lanes per 4-bank group, all 32 banks busy every phase).
__device__ __forceinline__ void gemm_mainloop(const __bf16* __restrict__ A,
                                              const __bf16* __restrict__ Bt,
                                              int bm, int bn,
                                              __bf16* At, __bf16* Bl,
                                              f32x4 acc[4][4]) {
  const int tid  = threadIdx.x;
  const int lane = tid & 63;
  const int l15  = lane & 15, quad = lane >> 4;
  const int wv   = tid >> 6;
  const int wm   = (wv >> 1) * 64, wn = (wv & 1) * 64;
  const int s0   = wv * 2;              // this wave's 2 segments (of 8) per tile
  const int srow = lane >> 2;           // 0..15 within segment
  const int scol = (lane & 3) << 3;     // 0,8,16,24
  for (int k0 = 0; k0 < 1024; k0 += 32) {
    __syncthreads();                    // all waves done reading LDS tiles
#pragma unroll
    for (int ss = 0; ss < 2; ss++) {
      const int s   = s0 + ss;
      const int row = s * 16 + srow;
      const __bf16* ga = A  + (size_t)(bm + row) * 1024 + k0 + scol;
      const __bf16* gb = Bt + (size_t)(bn + row) * 1024 + k0 + scol;
      // LDS dest = uniform base + lane*16B; seg*512 + lane*8 == row*32 + col
      __builtin_amdgcn_global_load_lds(
          (const __attribute__((address_space(1))) void*)ga,
          (__attribute__((address_space(3))) void*)(At + s * 512), 16, 0, 0);
      __builtin_amdgcn_global_load_lds(
          (const __attribute__((address_space(1))) void*)gb,
          (__attribute__((address_space(3))) void*)(Bl + s * 512), 16, 0, 0);
    }
    __syncthreads();                    // compiler drains vmcnt before barrier
    bf16x8 af[4], bfr[4];
#pragma unroll
    for (int mt = 0; mt < 4; mt++)
      af[mt] = *(const bf16x8*)(At + (wm + mt * 16 + l15) * 32 + quad * 8);
#pragma unroll
    for (int nt = 0; nt < 4; nt++)
      bfr[nt] = *(const bf16x8*)(Bl + (wn + nt * 16 + l15) * 32 + quad * 8);
#pragma unroll
    for (int mt = 0; mt < 4; mt++)
#pragma unroll
      for (int nt = 0; nt < 4; nt++)
        acc[mt][nt] = __builtin_amdgcn_mfma_f32_16x16x32_bf16(
            af[mt], bfr[nt], acc[mt][nt], 0, 0, 0);
  }
}

// ---------------- QKV projection (Q pre-scaled by 1/8) ----------------
__global__ __launch_bounds__(256) void k_gemm_qkv(const __bf16* __restrict__ xbf,
    const __bf16* __restrict__ wt_all, __bf16* __restrict__ qws,
    __bf16* __restrict__ kws, __bf16* __restrict__ vtws) {
  __shared__ __bf16 At[128 * 32];
  __shared__ __bf16 Bl[128 * 32];
  const int which = blockIdx.z;
  const __bf16* wt = wt_all + (size_t)which * DMODEL * DMODEL;
  const int bm = blockIdx.y * 128, bn = blockIdx.x * 128;
  f32x4 acc[4][4];
  const f32x4 z = {0.f, 0.f, 0.f, 0.f};
#pragma unroll
  for (int mt = 0; mt < 4; mt++)
#pragma unroll
    for (int nt = 0; nt < 4; nt++) acc[mt][nt] = z;
  gemm_mainloop(xbf, wt, bm, bn, At, Bl, acc);
  const int lane = threadIdx.x & 63;
  const int l15 = lane & 15, quad = lane >> 4;
  const int wv = threadIdx.x >> 6;
  const int wm = (wv >> 1) * 64, wn = (wv & 1) * 64;
#pragma unroll
  for (int mt = 0; mt < 4; mt++)
#pragma unroll
    for (int nt = 0; nt < 4; nt++)
#pragma unroll
      for (int r = 0; r < 4; r++) {
        int m = bm + wm + mt * 16 + quad * 4 + r;
        int n = bn + wn + nt * 16 + l15;
        int b = m >> 11, t = m & 2047;
        int h = n >> 6,  d = n & 63;
        int bh = b * 16 + h;
        float av = acc[mt][nt][r];
        if (which == 0)      qws[((size_t)bh * TSEQ + t) * HD + d] = (__bf16)(av * 0.125f);
        else if (which == 1) kws[((size_t)bh * TSEQ + t) * HD + d] = (__bf16)av;
        else                 vtws[((size_t)bh * HD + d) * VSTRIDE + t] = (__bf16)av;
      }
}

// ---------------- flash attention: LDS-staged K/V shared by 4 waves ----------------
__global__ __launch_bounds__(256) void k_attn(const __bf16* __restrict__ qws,
    const __bf16* __restrict__ kws, const __bf16* __restrict__ vtws,
    __bf16* __restrict__ ctx) {
  const int qb0 = blockIdx.x, qb1 = 31 - qb0;
  const int bh  = blockIdx.y;
  const int tid = threadIdx.x;
  const int lane = tid & 63, wv = tid >> 6;
  const int l15 = lane & 15, quad = lane >> 4;
  const __bf16* qp = qws  + (size_t)bh * TSEQ * HD;
  const __bf16* kp = kws  + (size_t)bh * TSEQ * HD;
  const __bf16* vp = vtws + (size_t)bh * HD * VSTRIDE;
  const int b = bh >> 4, h = bh & 15;

  __shared__ __bf16 kbuf[2][64 * LSTR];
  __shared__ __bf16 vbuf[2][64 * LSTR];
  __shared__ __bf16 plds[4][16 * 68];

  const f32x4 z = {0.f, 0.f, 0.f, 0.f};
  const int sr = tid >> 3, sc = (tid & 7) * 8;

  const int qr0a = qb0 * 64 + wv * 16;
  const int qr0b = qb1 * 64 + wv * 16;
  bf16x8 aq0[2], aq1[2];
#pragma unroll
  for (int kb = 0; kb < 2; kb++) {
    aq0[kb] = *(const bf16x8*)(qp + (size_t)(qr0a + l15) * HD + kb * 32 + quad * 8);
    aq1[kb] = *(const bf16x8*)(qp + (size_t)(qr0b + l15) * HD + kb * 32 + quad * 8);
  }

  bf16x8 kreg[2], vreg[2];
  kreg[0] = *(const bf16x8*)(kp + (size_t)sr * HD + sc);
  kreg[1] = *(const bf16x8*)(kp + (size_t)(sr + 32) * HD + sc);
  vreg[0] = *(const bf16x8*)(vp + (size_t)sr * VSTRIDE + sc);
  vreg[1] = *(const bf16x8*)(vp + (size_t)(sr + 32) * VSTRIDE + sc);
  *(bf16x8*)(kbuf[0] + sr * LSTR + sc)        = kreg[0];
  *(bf16x8*)(kbuf[0] + (sr + 32) * LSTR + sc) = kreg[1];
  *(bf16x8*)(vbuf[0] + sr * LSTR + sc)        = vreg[0];
  *(bf16x8*)(vbuf[0] + (sr + 32) * LSTR + sc) = vreg[1];
  __syncthreads();

  float lpart[4] = {0.f, 0.f, 0.f, 0.f};
  f32x4 acc[4];
#pragma unroll
  for (int dt = 0; dt < 4; dt++) acc[dt] = z;

  for (int s = 0; s < 33; s++) {
    const int cur = s & 1;
    const bool h0 = (s <= qb0);
    const bool masked = (s == qb0) || (s == 32);

    if (s + 1 < 33) {
      const int ktn = (s + 1 <= qb0) ? (s + 1) * 64 : (s - qb0) * 64;
      kreg[0] = *(const bf16x8*)(kp + (size_t)(ktn + sr) * HD + sc);
      kreg[1] = *(const bf16x8*)(kp + (size_t)(ktn + sr + 32) * HD + sc);
      vreg[0] = *(const bf16x8*)(vp + (size_t)sr * VSTRIDE + ktn + sc);
      vreg[1] = *(const bf16x8*)(vp + (size_t)(sr + 32) * VSTRIDE + ktn + sc);
    }

    const __bf16* kb_ = kbuf[cur];
    const __bf16* vb_ = vbuf[cur];
    f32x4 sarr[4];
#pragma unroll
    for (int nt = 0; nt < 4; nt++) sarr[nt] = z;
#pragma unroll
    for (int nt = 0; nt < 4; nt++)
#pragma unroll
      for (int kb = 0; kb < 2; kb++) {
        bf16x8 bk = *(const bf16x8*)(kb_ + (nt * 16 + l15) * LSTR + kb * 32 + quad * 8);
        bf16x8 a  = h0 ? aq0[kb] : aq1[kb];
        sarr[nt] = __builtin_amdgcn_mfma_f32_16x16x32_bf16(a, bk, sarr[nt], 0, 0, 0);
      }
    if (masked) {
#pragma unroll
      for (int r = 0; r < 4; r++) {
        const int qloc = wv * 16 + quad * 4 + r;
#pragma unroll
        for (int nt = 0; nt < 4; nt++) {
          int kloc = nt * 16 + l15;
          float p = (kloc <= qloc) ? __expf(sarr[nt][r]) : 0.f;
          lpart[r] += p;
          plds[wv][(quad * 4 + r) * 68 + nt * 16 + l15] = (__bf16)p;
        }
      }
    } else {
#pragma unroll
      for (int r = 0; r < 4; r++)
#pragma unroll
        for (int nt = 0; nt < 4; nt++) {
          float p = __expf(sarr[nt][r]);
          lpart[r] += p;
          plds[wv][(quad * 4 + r) * 68 + nt * 16 + l15] = (__bf16)p;
        }
    }
#pragma unroll
    for (int kb = 0; kb < 2; kb++) {
      bf16x8 ap = *(const bf16x8*)(&plds[wv][l15 * 68 + kb * 32 + quad * 8]);
#pragma unroll
      for (int dt = 0; dt < 4; dt++) {
        bf16x8 bvv = *(const bf16x8*)(vb_ + (dt * 16 + l15) * LSTR + kb * 32 + quad * 8);
        acc[dt] = __builtin_amdgcn_mfma_f32_16x16x32_bf16(ap, bvv, acc[dt], 0, 0, 0);
      }
    }

    if (s + 1 < 33) {
      const int nxt = cur ^ 1;
      *(bf16x8*)(kbuf[nxt] + sr * LSTR + sc)        = kreg[0];
      *(bf16x8*)(kbuf[nxt] + (sr + 32) * LSTR + sc) = kreg[1];
      *(bf16x8*)(vbuf[nxt] + sr * LSTR + sc)        = vreg[0];
      *(bf16x8*)(vbuf[nxt] + (sr + 32) * LSTR + sc) = vreg[1];
    }
    __syncthreads();

    if (masked) {
      const int qr0 = h0 ? qr0a : qr0b;
#pragma unroll
      for (int r = 0; r < 4; r++) {
        float l = lpart[r];
        l += __shfl_xor(l, 1, 64);
        l += __shfl_xor(l, 2, 64);
        l += __shfl_xor(l, 4, 64);
        l += __shfl_xor(l, 8, 64);
        float linv = 1.f / l;
        const int qrow = qr0 + quad * 4 + r;
#pragma unroll
        for (int dt = 0; dt < 4; dt++)
          ctx[((size_t)(b * TSEQ + qrow)) * DMODEL + h * 64 + dt * 16 + l15] =
              (__bf16)(acc[dt][r] * linv);
        lpart[r] = 0.f;
      }
#pragma unroll
      for (int dt = 0; dt < 4; dt++) acc[dt] = z;
    }
  }
}

// ---------------- output projection + bias (fp32 out) ----------------
__global__ __launch_bounds__(256) void k_gemm_out(const __bf16* __restrict__ ctx,
    const __bf16* __restrict__ wot, const float* __restrict__ bo,
    float* __restrict__ out) {
  __shared__ __bf16 At[128 * 32];
  __shared__ __bf16 Bl[128 * 32];
  const int bm = blockIdx.y * 128, bn = blockIdx.x * 128;
  f32x4 acc[4][4];
  const f32x4 z = {0.f, 0.f, 0.f, 0.f};
#pragma unroll
  for (int mt = 0; mt < 4; mt++)
#pragma unroll
    for (int nt = 0; nt < 4; nt++) acc[mt][nt] = z;
  gemm_mainloop(ctx, wot, bm, bn, At, Bl, acc);
  const int lane = threadIdx.x & 63;
  const int l15 = lane & 15, quad = lane >> 4;
  const int wv = threadIdx.x >> 6;
  const int wm = (wv >> 1) * 64, wn = (wv & 1) * 64;
#pragma unroll
  for (int mt = 0; mt < 4; mt++)
#pragma unroll
    for (int nt = 0; nt < 4; nt++)
#pragma unroll
      for (int r = 0; r < 4; r++) {
        int m = bm + wm + mt * 16 + quad * 4 + r;
        int n = bn + wn + nt * 16 + l15;
        out[(size_t)m * DMODEL + n] = acc[mt][nt][r] + bo[n];
      }
}

extern "C" void kernel_launch(void* const* d_in, const int* in_sizes, int n_in,
                              void* d_out, int out_size, void* d_ws, size_t ws_size,
                              hipStream_t stream) {
  const float* x  = (const float*)d_in[0];
  const float* Wq = (const float*)d_in[1];
  const float* Wk = (const float*)d_in[2];
  const float* Wv = (const float*)d_in[3];
  const float* Wo = (const float*)d_in[4];
  const float* bo = (const float*)d_in[5];
  float* out = (float*)d_out;

  __bf16* xbf  = (__bf16*)d_ws;                       // 4096*1024
  __bf16* wt   = xbf  + (size_t)4096 * 1024;          // 4 * 1024*1024
  __bf16* qws  = wt   + (size_t)4 * 1024 * 1024;      // [32][2048][64]
  __bf16* kws  = qws  + (size_t)32 * 2048 * 64;
  __bf16* vtws = kws  + (size_t)32 * 2048 * 64;       // [32][64][VSTRIDE]
  __bf16* ctx  = xbf;                                 // aliases xbf (dead after QKV)

  k_convert_x<<<4096, 256, 0, stream>>>(x, xbf);
  k_transpose_w<<<dim3(32, 32, 4), dim3(32, 32), 0, stream>>>(Wq, Wk, Wv, Wo, wt);
  k_gemm_qkv<<<dim3(8, 32, 3), 256, 0, stream>>>(xbf, wt, qws, kws, vtws);
  k_attn<<<dim3(16, 32), 256, 0, stream>>>(qws, kws, vtws, ctx);
  k_gemm_out<<<dim3(8, 32), 256, 0, stream>>>(ctx, wt + (size_t)3 * 1024 * 1024, bo, out);
}